// Round 8
// baseline (445.866 us; speedup 1.0000x reference)
//
#include <hip/hip_runtime.h>
#include <hip/hip_bf16.h>

using bf16 = __hip_bfloat16;
typedef __attribute__((ext_vector_type(8))) short bf16x8;
typedef __attribute__((ext_vector_type(4))) float f32x4;

#define DDIM 1024

__device__ __forceinline__ void gload16(const bf16* g, bf16* l) {
    __builtin_amdgcn_global_load_lds(
        (const __attribute__((address_space(1))) void*)g,
        (__attribute__((address_space(3))) void*)l, 16, 0, 0);
}
__device__ __forceinline__ short f2b(float f) {
    return (short)__bfloat16_as_ushort(__float2bfloat16(f));
}

__global__ void prep_kernel(const float* __restrict__ W, const float* __restrict__ w,
                            const float* __restrict__ b, const float* __restrict__ nstr,
                            const float* __restrict__ nraw,
                            float* __restrict__ dco, float* __restrict__ ad2,
                            bf16* __restrict__ Wb) {
    int o = blockIdx.x;
    int lane = threadIdx.x;
    const float* Wrow = W + (size_t)o * DDIM;
    bf16* Wbrow = Wb + (size_t)o * DDIM;
    float s = 0.f;
    for (int j = lane; j < DDIM; j += 64) {
        float wv = Wrow[j];
        Wbrow[j] = __float2bfloat16(wv);
        float m = wv * w[j];
        s += m * m;
    }
#pragma unroll
    for (int off = 32; off; off >>= 1) s += __shfl_down(s, off);
    if (lane == 0) {
        dco[o] = rsqrtf(s + 1e-8f);
        ad2[o] = nraw[o] * nstr[0] + b[o];
    }
}

// ---- 256x256x(BK=64) 8-phase GEMM, C[n][o] = sum_j A[n][j]*W[o][j] ----
// R5 schedule, m201 sync idiom: BARE s_barrier builtin + UN-CLOBBERED waitcnt asm.
// (R5's asm-"memory"-clobber wrappers forced vmcnt(0)+lgkmcnt(0) drains at every
// sync point — the __syncthreads-style drain the 8-phase exists to avoid.)
#define BAR()  __builtin_amdgcn_s_barrier()
#define VMW(n) asm volatile("s_waitcnt vmcnt(" #n ")")
#define LGW()  asm volatile("s_waitcnt lgkmcnt(0)")

template<int PASS>
__global__ __launch_bounds__(512, 2) void gemm8p(
    const float* __restrict__ Af, const bf16* __restrict__ Ab,
    const bf16* __restrict__ Bw,
    const float* __restrict__ wst, const float* __restrict__ bias,
    const float* __restrict__ dco, const float* __restrict__ ad2,
    bf16* __restrict__ Cb, float* __restrict__ Cf)
{
    __shared__ bf16 sA[2][2][256 * 32];   // 64 KiB
    __shared__ bf16 sB[2][2][256 * 32];   // 64 KiB

    const int tid  = threadIdx.x;
    const int lane = tid & 63;
    const int wid  = tid >> 6;
    const int wr   = wid >> 2, wc = wid & 3;      // 2 x 4 waves
    const int r16  = lane & 15, kh = lane >> 4;
    const int fso  = (kh ^ ((r16 >> 1) & 3)) * 8; // swizzled frag slot (elems)

    int bx  = blockIdx.x;                          // 1024 blocks
    int swz = (bx & 7) * 128 + (bx >> 3);          // bijective XCD swizzle
    int brow = swz >> 2, bcol = swz & 3;

    const float* Asrc_f = Af + (size_t)(brow * 256) * DDIM;
    const bf16*  Asrc_b = Ab + (size_t)(brow * 256) * DDIM;
    const bf16*  Bsrc   = Bw + (size_t)(bcol * 256) * DDIM;

    const int sr  = tid >> 2;                      // staging row 0..127 (and +128)
    const int ssl = (tid & 3) ^ ((sr >> 1) & 3);   // swizzled 16B source slot

    f32x4 acc[8][4];
#pragma unroll
    for (int m = 0; m < 8; ++m)
#pragma unroll
        for (int n = 0; n < 4; ++n) acc[m][n] = (f32x4){0.f, 0.f, 0.f, 0.f};

    bf16x8 aF[4], bF[4];
    float4 gA0, gA1, gA2, gA3;   // PASS1 A-prefetch regs (K-half 0 group)
    float4 gB0, gB1, gB2, gB3;   // PASS1 A-prefetch regs (K-half 1 group)

#define STAGE_B(buf, kt, ks) do { \
    const bf16* _s = Bsrc + (size_t)sr * DDIM + ((kt) * 64 + (ks) * 32 + ssl * 8); \
    gload16(_s,               &sB[buf][ks][tid * 8]); \
    gload16(_s + 128 * DDIM,  &sB[buf][ks][(tid + 512) * 8]); \
} while (0)

#define STAGE_A_G(buf, kt, ks) do { \
    const bf16* _s = Asrc_b + (size_t)sr * DDIM + ((kt) * 64 + (ks) * 32 + ssl * 8); \
    gload16(_s,               &sA[buf][ks][tid * 8]); \
    gload16(_s + 128 * DDIM,  &sA[buf][ks][(tid + 512) * 8]); \
} while (0)

#define LOAD_A_F(g0, g1, g2, g3, kt, ks) do { \
    const float* _p = Asrc_f + (size_t)sr * DDIM + ((kt) * 64 + (ks) * 32 + (tid & 3) * 8); \
    g0 = ((const float4*)_p)[0]; g1 = ((const float4*)_p)[1]; \
    const float* _q = _p + 128 * DDIM; \
    g2 = ((const float4*)_q)[0]; g3 = ((const float4*)_q)[1]; \
} while (0)

#define WRITE_A(buf, ks, g0, g1, g2, g3) do { \
    bf16x8 _pk; \
    _pk[0]=f2b(g0.x); _pk[1]=f2b(g0.y); _pk[2]=f2b(g0.z); _pk[3]=f2b(g0.w); \
    _pk[4]=f2b(g1.x); _pk[5]=f2b(g1.y); _pk[6]=f2b(g1.z); _pk[7]=f2b(g1.w); \
    *(bf16x8*)&sA[buf][ks][sr * 32 + ssl * 8] = _pk; \
    _pk[0]=f2b(g2.x); _pk[1]=f2b(g2.y); _pk[2]=f2b(g2.z); _pk[3]=f2b(g2.w); \
    _pk[4]=f2b(g3.x); _pk[5]=f2b(g3.y); _pk[6]=f2b(g3.z); _pk[7]=f2b(g3.w); \
    *(bf16x8*)&sA[buf][ks][(sr + 128) * 32 + ssl * 8] = _pk; \
} while (0)

#define RD_A(buf, ks, mh) do { \
    _Pragma("unroll") for (int _m = 0; _m < 4; ++_m) \
        aF[_m] = *(const bf16x8*)&sA[buf][ks][(wr * 128 + (mh) * 64 + _m * 16 + r16) * 32 + fso]; \
} while (0)

#define RD_B(buf, ks) do { \
    _Pragma("unroll") for (int _n = 0; _n < 4; ++_n) \
        bF[_n] = *(const bf16x8*)&sB[buf][ks][(wc * 64 + _n * 16 + r16) * 32 + fso]; \
} while (0)

#define MFMA16(mh) do { \
    __builtin_amdgcn_s_setprio(1); \
    _Pragma("unroll") for (int _m = 0; _m < 4; ++_m) { \
        const bf16x8* _af = (_m == 0) ? &aF[0] : (_m == 1) ? &aF[1] : (_m == 2) ? &aF[2] : &aF[3]; \
        acc[(mh)*4+_m][0] = __builtin_amdgcn_mfma_f32_16x16x32_bf16(*_af, bF[0], acc[(mh)*4+_m][0], 0, 0, 0); \
        acc[(mh)*4+_m][1] = __builtin_amdgcn_mfma_f32_16x16x32_bf16(*_af, bF[1], acc[(mh)*4+_m][1], 0, 0, 0); \
        acc[(mh)*4+_m][2] = __builtin_amdgcn_mfma_f32_16x16x32_bf16(*_af, bF[2], acc[(mh)*4+_m][2], 0, 0, 0); \
        acc[(mh)*4+_m][3] = __builtin_amdgcn_mfma_f32_16x16x32_bf16(*_af, bF[3], acc[(mh)*4+_m][3], 0, 0, 0); \
    } \
    __builtin_amdgcn_s_setprio(0); \
} while (0)

    // ---------------- prologue ----------------
    if constexpr (PASS == 1) {
        LOAD_A_F(gA0, gA1, gA2, gA3, 0, 0);
        LOAD_A_F(gB0, gB1, gB2, gB3, 0, 1);
        STAGE_B(0, 0, 0); STAGE_B(0, 0, 1);
        WRITE_A(0, 0, gA0, gA1, gA2, gA3);
        WRITE_A(0, 1, gB0, gB1, gB2, gB3);
        LOAD_A_F(gA0, gA1, gA2, gA3, 1, 0);    // consumed at ph0 (t1.AK0)
        LOAD_A_F(gB0, gB1, gB2, gB3, 1, 1);    // consumed at ph2 (t1.AK1)
        LGW();
        VMW(8);                                 // retire t0.B halves; LA groups in flight
        BAR();
    } else {
        STAGE_A_G(0, 0, 0); STAGE_B(0, 0, 0);
        STAGE_A_G(0, 0, 1); STAGE_B(0, 0, 1);
        VMW(4);                                 // t0.K0 landed; t0.K1 in flight
        BAR();
    }

    // ---------------- main loop: 8 iters x 2 K-tiles ----------------
    for (int i = 0; i < 8; ++i) {
        int t1 = 2 * i + 1;
        int t2 = 2 * i + 2; if (t2 > 15) t2 = 15;   // tail clamp (stages never read)
        int t3 = 2 * i + 3; if (t3 > 15) t3 = 15;

        // ph0: compute (t0 buf0, ks0, mh0); stage t1.AK0 -> buf1
        RD_A(0, 0, 0); RD_B(0, 0);
        if constexpr (PASS == 1) {
            WRITE_A(1, 0, gA0, gA1, gA2, gA3);
            LOAD_A_F(gA0, gA1, gA2, gA3, t2, 0);
            LGW();
        } else {
            STAGE_A_G(1, t1, 0);
        }
        BAR(); MFMA16(0); BAR();

        // ph1: (ks0, mh1); stage t1.BK0 -> buf1
        RD_A(0, 0, 1);
        STAGE_B(1, t1, 0);
        BAR(); MFMA16(1);
        if constexpr (PASS == 1) { VMW(6); } else { VMW(4); }
        BAR();

        // ph2: (ks1, mh0); stage t1.AK1 -> buf1
        RD_A(0, 1, 0); RD_B(0, 1);
        if constexpr (PASS == 1) {
            WRITE_A(1, 1, gB0, gB1, gB2, gB3);
            LOAD_A_F(gB0, gB1, gB2, gB3, t2, 1);
            LGW();
        } else {
            STAGE_A_G(1, t1, 1);
        }
        BAR(); MFMA16(0); BAR();

        // ph3: (ks1, mh1); stage t1.BK1 -> buf1
        RD_A(0, 1, 1);
        STAGE_B(1, t1, 1);
        BAR(); MFMA16(1);
        if constexpr (PASS == 1) { VMW(6); } else { VMW(4); }
        BAR();

        // ph4: compute (t1 buf1, ks0, mh0); stage t2.AK0 -> buf0
        RD_A(1, 0, 0); RD_B(1, 0);
        if constexpr (PASS == 1) {
            WRITE_A(0, 0, gA0, gA1, gA2, gA3);
            LOAD_A_F(gA0, gA1, gA2, gA3, t3, 0);
            LGW();
        } else {
            STAGE_A_G(0, t2, 0);
        }
        BAR(); MFMA16(0); BAR();

        // ph5: (ks0, mh1); stage t2.BK0 -> buf0
        RD_A(1, 0, 1);
        STAGE_B(0, t2, 0);
        BAR(); MFMA16(1);
        if constexpr (PASS == 1) { VMW(6); } else { VMW(4); }
        BAR();

        // ph6: (ks1, mh0); stage t2.AK1 -> buf0
        RD_A(1, 1, 0); RD_B(1, 1);
        if constexpr (PASS == 1) {
            WRITE_A(0, 1, gB0, gB1, gB2, gB3);
            LOAD_A_F(gB0, gB1, gB2, gB3, t3, 1);
            LGW();
        } else {
            STAGE_A_G(0, t2, 1);
        }
        BAR(); MFMA16(0); BAR();

        // ph7: (ks1, mh1); stage t2.BK1 -> buf0
        RD_A(1, 1, 1);
        STAGE_B(0, t2, 1);
        BAR(); MFMA16(1);
        if constexpr (PASS == 1) { VMW(6); } else { VMW(4); }
        BAR();
    }

    // ---------------- epilogue ----------------
    int crb = brow * 256 + wr * 128 + kh * 4;
    int ccb = bcol * 256 + wc * 64 + r16;
#pragma unroll
    for (int n = 0; n < 4; ++n) {
        int col = ccb + n * 16;
        float cm, ca;
        if constexpr (PASS == 1) { cm = wst[col]; ca = bias[col]; }
        else                     { cm = dco[col]; ca = ad2[col]; }
#pragma unroll
        for (int m = 0; m < 8; ++m) {
#pragma unroll
            for (int j = 0; j < 4; ++j) {
                size_t idx = (size_t)(crb + m * 16 + j) * DDIM + col;
                float v = acc[m][n][j];
                if constexpr (PASS == 1) {
                    v = (v + ca) * cm;
                    Cb[idx] = __float2bfloat16(v);
                } else {
                    v = v * cm + ca;
                    v = (v >= 0.f) ? v : 0.01f * v;
                    Cf[idx] = v;
                }
            }
        }
    }
#undef STAGE_B
#undef STAGE_A_G
#undef LOAD_A_F
#undef WRITE_A
#undef RD_A
#undef RD_B
#undef MFMA16
}

extern "C" void kernel_launch(void* const* d_in, const int* in_sizes, int n_in,
                              void* d_out, int out_size, void* d_ws, size_t ws_size,
                              hipStream_t stream) {
    const float* x  = (const float*)d_in[0];
    const float* w  = (const float*)d_in[1];
    const float* W  = (const float*)d_in[2];
    const float* b  = (const float*)d_in[3];
    const float* ns = (const float*)d_in[4];
    const float* nr = (const float*)d_in[5];
    float* out = (float*)d_out;

    float* dco = (float*)d_ws;
    float* ad2 = dco + DDIM;
    bf16*  Wb  = (bf16*)((char*)d_ws + 8192);
    bf16*  t   = (bf16*)((char*)d_ws + 8192 + 2097152);

    int M = in_sizes[0] / DDIM;                     // 65536
    int grid = (M / 256) * (DDIM / 256);            // 1024

    prep_kernel<<<DDIM, 64, 0, stream>>>(W, w, b, ns, nr, dco, ad2, Wb);
    gemm8p<1><<<grid, 512, 0, stream>>>(x, nullptr, Wb, w, b, dco, ad2, t, nullptr);
    gemm8p<2><<<grid, 512, 0, stream>>>(nullptr, t, Wb, w, b, dco, ad2, nullptr, out);
}